// Round 1
// baseline (372.248 us; speedup 1.0000x reference)
//
#include <hip/hip_runtime.h>
#include <hip/hip_bf16.h>

// Problem constants
#define B_    32
#define C_    256     // Cin == Cout
#define H_    56
#define W_    56
#define HP    58      // padded H
#define WPAD  58      // padded W
#define HW    3136    // H_*W_
#define CHW   802816  // C_*H_*W_
#define M_TOT 100352  // B_*H_*W_

typedef __bf16 bf16;
typedef __bf16 bf16x8 __attribute__((ext_vector_type(8)));
typedef float floatx4 __attribute__((ext_vector_type(4)));

#define XPAD_ELEMS (B_ * HP * WPAD * C_)        // 27,557,888
#define XPAD_BYTES (XPAD_ELEMS * 2)             // 55,115,776
#define WPK_ELEMS  (C_ * 9 * C_)                // 589,824
#define WPK_BYTES  (WPK_ELEMS * 2)              // 1,179,648

// ---------------------------------------------------------------------------
// Pack weights: wter[co][s][ci] bf16 (K-contiguous per shift), alpha[co] fp32
// ---------------------------------------------------------------------------
__global__ __launch_bounds__(256) void pack_w_kernel(const float* __restrict__ w1,
                                                     const float* __restrict__ w2,
                                                     bf16* __restrict__ wp,
                                                     float* __restrict__ alpha) {
  const int co = blockIdx.x;
  const int ci = threadIdx.x;
  const int base = (co * C_ + ci) * 9;
  float sabs = 0.f;
#pragma unroll
  for (int s = 0; s < 9; ++s) {
    const float a = w1[base + s];
    const float b = w2[base + s];
    const float sa = (a > 0.f) ? 1.f : ((a < 0.f) ? -1.f : 0.f);
    const float sb = (b > 0.f) ? 1.f : ((b < 0.f) ? -1.f : 0.f);
    wp[(co * 9 + s) * C_ + ci] = (bf16)(0.5f * (sa + sb));
    sabs += fabsf(a) + fabsf(b);
  }
#pragma unroll
  for (int off = 32; off > 0; off >>= 1) sabs += __shfl_down(sabs, off, 64);
  __shared__ float red[4];
  if ((threadIdx.x & 63) == 0) red[threadIdx.x >> 6] = sabs;
  __syncthreads();
  if (threadIdx.x == 0)
    alpha[co] = (red[0] + red[1] + red[2] + red[3]) * (1.0f / 2304.0f);
}

// ---------------------------------------------------------------------------
// Pack input: sign(x) NCHW fp32 -> padded NHWC bf16 [B][58][58][C]
// LDS transpose tile: 64 ci x 64 x for one (b, y) row. 4 ci-tiles per row.
// ---------------------------------------------------------------------------
__global__ __launch_bounds__(256) void pack_x_kernel(const float* __restrict__ in,
                                                     bf16* __restrict__ xp) {
  __shared__ bf16 tile[64][65];  // +1 pad: conflict-free transposed reads
  const int bx = blockIdx.x;
  const int ct = bx & 3;
  const int y = (bx >> 2) % H_;
  const int b = bx / (H_ * 4);
  const int ci0 = ct * 64;
  const int tid = threadIdx.x;
#pragma unroll
  for (int it = 0; it < 16; ++it) {
    const int idx = it * 256 + tid;
    const int r = idx >> 6;    // ci offset 0..63
    const int xx = idx & 63;   // x 0..63 (56 valid)
    float v = 0.f;
    if (xx < W_) {
      const float f = in[((b * C_ + ci0 + r) * H_ + y) * W_ + xx];
      v = (f > 0.f) ? 1.f : ((f < 0.f) ? -1.f : 0.f);
    }
    tile[r][xx] = (bf16)v;
  }
  __syncthreads();
#pragma unroll
  for (int it = 0; it < 16; ++it) {
    const int idx = it * 256 + tid;
    const int xx = idx >> 6;
    const int cc = idx & 63;
    if (xx < W_) {
      xp[((b * HP + (y + 1)) * WPAD + (xx + 1)) * C_ + ci0 + cc] = tile[cc][xx];
    }
  }
}

// ---------------------------------------------------------------------------
// Implicit-GEMM conv: C[co][m] = sum_{s,ci} W[co][s][ci] * Xpad[m(+s)][ci]
// Tile 128(co) x 128(m), BK=64, 4 waves of 64x64, mfma_f32_16x16x32_bf16.
// ---------------------------------------------------------------------------
__global__ __launch_bounds__(256, 2) void gemm_kernel(const bf16* __restrict__ xp,
                                                      const bf16* __restrict__ wp,
                                                      const float* __restrict__ alpha,
                                                      float* __restrict__ out) {
  __shared__ bf16 sA[128 * 64];  // weight tile  [co 128][k 64]
  __shared__ bf16 sB[128 * 64];  // input tile   [m 128][k 64]
  const int tid = threadIdx.x;
  const int m0 = blockIdx.x * 128;
  const int co0 = blockIdx.y * 128;
  const int srow = tid >> 3;   // staging row 0..31 (+32*i)
  const int scol = tid & 7;    // staging col chunk (8 bf16 each)

  const bf16* wsrc[4];
  const bf16* xsrc[4];
#pragma unroll
  for (int i = 0; i < 4; ++i) {
    const int m = m0 + srow + 32 * i;
    const int b = m / HW;
    const int rem = m - b * HW;
    const int y = rem / W_;
    const int x = rem - y * W_;
    // padded NHWC base at (yp=y, xp=x): shift s adds ((s/3)*WPAD + s%3)*C_
    xsrc[i] = xp + ((b * HP + y) * WPAD + x) * C_ + scol * 8;
    wsrc[i] = wp + (co0 + srow + 32 * i) * 9 * C_ + scol * 8;
  }

  floatx4 acc[4][4] = {};

  const int lane = tid & 63;
  const int wave = tid >> 6;
  const int wm = wave >> 1;   // co 64-half
  const int wn = wave & 1;    // m 64-half
  const int lrow = lane & 15;
  const int quad = lane >> 4;
  const char* sAc = (const char*)sA;
  const char* sBc = (const char*)sB;
  const int aoff = (wm * 64 + lrow) * 128 + quad * 16;
  const int boff = (wn * 64 + lrow) * 128 + quad * 16;

  for (int s = 0; s < 9; ++s) {
    const int shoff = ((s / 3) * WPAD + (s % 3)) * C_;
    for (int kc = 0; kc < 4; ++kc) {
      const int ci0 = kc * 64;
      __syncthreads();  // previous tile's MFMA reads done
#pragma unroll
      for (int i = 0; i < 4; ++i) {
        __builtin_amdgcn_global_load_lds(
            (const __attribute__((address_space(1))) void*)(wsrc[i] + s * C_ + ci0),
            (__attribute__((address_space(3))) void*)((char*)sA + i * 4096 + tid * 16),
            16, 0, 0);
      }
#pragma unroll
      for (int i = 0; i < 4; ++i) {
        __builtin_amdgcn_global_load_lds(
            (const __attribute__((address_space(1))) void*)(xsrc[i] + shoff + ci0),
            (__attribute__((address_space(3))) void*)((char*)sB + i * 4096 + tid * 16),
            16, 0, 0);
      }
      __syncthreads();  // compiler emits vmcnt(0) before s_barrier -> data ready
#pragma unroll
      for (int kf = 0; kf < 2; ++kf) {
        bf16x8 af[4], bfv[4];
#pragma unroll
        for (int i = 0; i < 4; ++i)
          af[i] = *(const bf16x8*)(sAc + aoff + i * 2048 + kf * 64);
#pragma unroll
        for (int j = 0; j < 4; ++j)
          bfv[j] = *(const bf16x8*)(sBc + boff + j * 2048 + kf * 64);
#pragma unroll
        for (int i = 0; i < 4; ++i)
#pragma unroll
          for (int j = 0; j < 4; ++j)
            acc[i][j] = __builtin_amdgcn_mfma_f32_16x16x32_bf16(af[i], bfv[j],
                                                                acc[i][j], 0, 0, 0);
      }
    }
  }

  // Epilogue: D row (quad*4+r) = co-frag dim, D col (lane&15) = spatial m dim.
  int ob[4];
#pragma unroll
  for (int j = 0; j < 4; ++j) {
    const int m = m0 + wn * 64 + j * 16 + lrow;
    const int b = m / HW;
    const int rem = m - b * HW;
    const int y = rem / W_;
    const int x = rem - y * W_;
    ob[j] = b * CHW + y * W_ + x;
  }
#pragma unroll
  for (int i = 0; i < 4; ++i) {
#pragma unroll
    for (int r = 0; r < 4; ++r) {
      const int co = co0 + wm * 64 + i * 16 + quad * 4 + r;
      const float sc = alpha[co];
#pragma unroll
      for (int j = 0; j < 4; ++j)
        out[ob[j] + co * HW] = acc[i][j][r] * sc;
    }
  }
}

// ---------------------------------------------------------------------------
extern "C" void kernel_launch(void* const* d_in, const int* in_sizes, int n_in,
                              void* d_out, int out_size, void* d_ws, size_t ws_size,
                              hipStream_t stream) {
  const float* input = (const float*)d_in[0];
  const float* w1 = (const float*)d_in[1];
  const float* w2 = (const float*)d_in[2];
  float* out = (float*)d_out;

  char* ws = (char*)d_ws;
  bf16* xp = (bf16*)ws;                              // 55,115,776 B
  bf16* wp = (bf16*)(ws + XPAD_BYTES);               // 1,179,648 B
  float* alpha = (float*)(ws + XPAD_BYTES + WPK_BYTES);  // 1,024 B

  hipMemsetAsync(xp, 0, XPAD_BYTES, stream);  // zero halo of padded input
  pack_w_kernel<<<C_, 256, 0, stream>>>(w1, w2, wp, alpha);
  pack_x_kernel<<<B_ * H_ * 4, 256, 0, stream>>>(input, xp);
  gemm_kernel<<<dim3(M_TOT / 128, C_ / 128), 256, 0, stream>>>(xp, wp, alpha, out);
}

// Round 2
// 291.532 us; speedup vs baseline: 1.2769x; 1.2769x over previous
//
#include <hip/hip_runtime.h>
#include <hip/hip_bf16.h>

// Problem constants
#define B_    32
#define C_    256     // Cin == Cout
#define H_    56
#define W_    56
#define HP    58      // padded H
#define WPAD  58      // padded W
#define HW    3136    // H_*W_
#define CHW   802816  // C_*H_*W_
#define M_TOT 100352  // B_*H_*W_

typedef __bf16 bf16;
typedef __bf16 bf16x8 __attribute__((ext_vector_type(8)));
typedef float floatx4 __attribute__((ext_vector_type(4)));

#define XPAD_ELEMS (B_ * HP * WPAD * C_)        // 27,557,888
#define XPAD_BYTES (XPAD_ELEMS * 2)             // 55,115,776
#define WPK_ELEMS  (C_ * 9 * C_)                // 589,824
#define WPK_BYTES  (WPK_ELEMS * 2)              // 1,179,648

// ---------------------------------------------------------------------------
// Pack weights: wter[co][s][ci] bf16 (K-contiguous per shift), alpha[co] fp32
// ---------------------------------------------------------------------------
__global__ __launch_bounds__(256) void pack_w_kernel(const float* __restrict__ w1,
                                                     const float* __restrict__ w2,
                                                     bf16* __restrict__ wp,
                                                     float* __restrict__ alpha) {
  const int co = blockIdx.x;
  const int ci = threadIdx.x;
  const int base = (co * C_ + ci) * 9;
  float sabs = 0.f;
#pragma unroll
  for (int s = 0; s < 9; ++s) {
    const float a = w1[base + s];
    const float b = w2[base + s];
    const float sa = (a > 0.f) ? 1.f : ((a < 0.f) ? -1.f : 0.f);
    const float sb = (b > 0.f) ? 1.f : ((b < 0.f) ? -1.f : 0.f);
    wp[(co * 9 + s) * C_ + ci] = (bf16)(0.5f * (sa + sb));
    sabs += fabsf(a) + fabsf(b);
  }
#pragma unroll
  for (int off = 32; off > 0; off >>= 1) sabs += __shfl_down(sabs, off, 64);
  __shared__ float red[4];
  if ((threadIdx.x & 63) == 0) red[threadIdx.x >> 6] = sabs;
  __syncthreads();
  if (threadIdx.x == 0)
    alpha[co] = (red[0] + red[1] + red[2] + red[3]) * (1.0f / 2304.0f);
}

// ---------------------------------------------------------------------------
// Pack input: sign(x) NCHW fp32 -> padded NHWC bf16 [B][58][58][C].
// One block per (b, padded-y). LDS transpose tile [x_pad][ci], row stride 264
// elems (528 B, 16B-aligned, bank-quad stride 4 -> conflict-free b128).
// Halo (x=0/57, y=0/57) zero-filled here; NO separate memset needed.
// ---------------------------------------------------------------------------
#define ROWP 264
__global__ __launch_bounds__(256) void pack_x_kernel(const float* __restrict__ in,
                                                     bf16* __restrict__ xp) {
  __shared__ bf16 row[58 * ROWP];  // 30,624 B
  const int yp = blockIdx.x % HP;
  const int b  = blockIdx.x / HP;
  const int tid = threadIdx.x;

  // zero-fill whole tile (covers halo + invalid-y rows)
  float4* rz = (float4*)row;
  const float4 z4 = make_float4(0.f, 0.f, 0.f, 0.f);
#pragma unroll
  for (int i = 0; i < 8; ++i) {
    const int idx = i * 256 + tid;
    if (idx < (58 * ROWP * 2) / 16) rz[idx] = z4;
  }
  __syncthreads();

  const int y = yp - 1;
  if (y >= 0 && y < H_) {
    const int x = tid & 63;     // lane-per-x: coalesced fp32 reads
    const int cig = tid >> 6;   // 0..3
    if (x < W_) {
#pragma unroll
      for (int it = 0; it < 8; ++it) {
        const int ci0 = it * 32 + cig * 8;
        bf16x8 v;
#pragma unroll
        for (int j = 0; j < 8; ++j) {
          const float f = in[((b * C_ + ci0 + j) * H_ + y) * W_ + x];
          v[j] = (bf16)((f > 0.f) ? 1.f : ((f < 0.f) ? -1.f : 0.f));
        }
        *(bf16x8*)&row[(x + 1) * ROWP + ci0] = v;  // 16B LDS write
      }
    }
  }
  __syncthreads();

  // write out full padded row: 58 x-slots x 512 B, b128 stores
  const int cc = tid & 31;   // 32 chunks = full 512 B ci-row
  const int xo = tid >> 5;   // 8 x per iter
  bf16* dst = xp + (size_t)(b * HP + yp) * WPAD * C_;
#pragma unroll
  for (int it = 0; it < 8; ++it) {
    const int xs = it * 8 + xo;
    if (xs < WPAD)
      *(float4*)(dst + xs * C_ + cc * 8) = *(const float4*)&row[xs * ROWP + cc * 8];
  }
}

// ---------------------------------------------------------------------------
// Implicit-GEMM conv: C[co][m] = sum_{s,ci} W[co][s][ci] * Xpad[m(+s)][ci]
// Tile 128(co) x 128(m), BK=64, 4 waves of 64x64, mfma_f32_16x16x32_bf16.
// LDS k-chunk XOR swizzle (chunk_lds = chunk_glob ^ (row&7)) kills the
// 16-way bank aliasing of the 128B-row layout. XCD-paired block decode.
// ---------------------------------------------------------------------------
__global__ __launch_bounds__(256, 2) void gemm_kernel(const bf16* __restrict__ xp,
                                                      const bf16* __restrict__ wp,
                                                      const float* __restrict__ alpha,
                                                      float* __restrict__ out) {
  __shared__ bf16 sA[128 * 64];  // weight tile  [co 128][k 64]
  __shared__ bf16 sB[128 * 64];  // input tile   [m 128][k 64]
  const int tid = threadIdx.x;

  // XCD-paired decode: blocks id and id+8 (same XCD slot stream) are the two
  // co-halves of the same m-tile -> X window fetched once per XCD L2.
  const int id = blockIdx.x;
  const int xcd = id & 7;
  const int l = id >> 3;
  const int co0 = (l & 1) * 128;
  const int m0 = ((l >> 1) * 8 + xcd) * 128;

  const int srow = tid >> 3;                       // staging row 0..31 (+32*i)
  const int scol = (tid & 7) ^ (srow & 7);         // XOR-swizzled source chunk

  const bf16* wsrc[4];
  const bf16* xsrc[4];
#pragma unroll
  for (int i = 0; i < 4; ++i) {
    const int m = m0 + srow + 32 * i;
    const int b = m / HW;
    const int rem = m - b * HW;
    const int y = rem / W_;
    const int x = rem - y * W_;
    // padded NHWC base at (yp=y, xp=x): shift s adds ((s/3)*WPAD + s%3)*C_
    xsrc[i] = xp + ((b * HP + y) * WPAD + x) * C_ + scol * 8;
    wsrc[i] = wp + (co0 + srow + 32 * i) * 9 * C_ + scol * 8;
  }

  floatx4 acc[4][4] = {};

  const int lane = tid & 63;
  const int wave = tid >> 6;
  const int wm = wave >> 1;   // co 64-half
  const int wn = wave & 1;    // m 64-half
  const int lrow = lane & 15;
  const int quad = lane >> 4;
  const int swk = lrow & 7;   // row swizzle key (row%8 == lrow%8 for all frags)
  const char* sAc = (const char*)sA;
  const char* sBc = (const char*)sB;
  const int abase = (wm * 64 + lrow) * 128;
  const int bbase = (wn * 64 + lrow) * 128;

  for (int s = 0; s < 9; ++s) {
    const int shoff = ((s / 3) * WPAD + (s % 3)) * C_;
    for (int kc = 0; kc < 4; ++kc) {
      const int ci0 = kc * 64;
      __syncthreads();  // previous tile's MFMA reads done
#pragma unroll
      for (int i = 0; i < 4; ++i) {
        __builtin_amdgcn_global_load_lds(
            (const __attribute__((address_space(1))) void*)(wsrc[i] + s * C_ + ci0),
            (__attribute__((address_space(3))) void*)((char*)sA + i * 4096 + tid * 16),
            16, 0, 0);
      }
#pragma unroll
      for (int i = 0; i < 4; ++i) {
        __builtin_amdgcn_global_load_lds(
            (const __attribute__((address_space(1))) void*)(xsrc[i] + shoff + ci0),
            (__attribute__((address_space(3))) void*)((char*)sB + i * 4096 + tid * 16),
            16, 0, 0);
      }
      __syncthreads();  // vmcnt(0) drained before barrier -> data ready
#pragma unroll
      for (int kf = 0; kf < 2; ++kf) {
        const int coff = (((kf << 2) + quad) ^ swk) << 4;  // swizzled chunk
        bf16x8 af[4], bfv[4];
#pragma unroll
        for (int i = 0; i < 4; ++i)
          af[i] = *(const bf16x8*)(sAc + abase + i * 2048 + coff);
#pragma unroll
        for (int j = 0; j < 4; ++j)
          bfv[j] = *(const bf16x8*)(sBc + bbase + j * 2048 + coff);
#pragma unroll
        for (int i = 0; i < 4; ++i)
#pragma unroll
          for (int j = 0; j < 4; ++j)
            acc[i][j] = __builtin_amdgcn_mfma_f32_16x16x32_bf16(af[i], bfv[j],
                                                                acc[i][j], 0, 0, 0);
      }
    }
  }

  // Epilogue: D row (quad*4+r) = co-frag dim, D col (lane&15) = spatial m dim.
  int ob[4];
#pragma unroll
  for (int j = 0; j < 4; ++j) {
    const int m = m0 + wn * 64 + j * 16 + lrow;
    const int b = m / HW;
    const int rem = m - b * HW;
    const int y = rem / W_;
    const int x = rem - y * W_;
    ob[j] = b * CHW + y * W_ + x;
  }
#pragma unroll
  for (int i = 0; i < 4; ++i) {
#pragma unroll
    for (int r = 0; r < 4; ++r) {
      const int co = co0 + wm * 64 + i * 16 + quad * 4 + r;
      const float sc = alpha[co];
#pragma unroll
      for (int j = 0; j < 4; ++j)
        out[ob[j] + co * HW] = acc[i][j][r] * sc;
    }
  }
}

// ---------------------------------------------------------------------------
extern "C" void kernel_launch(void* const* d_in, const int* in_sizes, int n_in,
                              void* d_out, int out_size, void* d_ws, size_t ws_size,
                              hipStream_t stream) {
  const float* input = (const float*)d_in[0];
  const float* w1 = (const float*)d_in[1];
  const float* w2 = (const float*)d_in[2];
  float* out = (float*)d_out;

  char* ws = (char*)d_ws;
  bf16* xp = (bf16*)ws;                              // 55,115,776 B
  bf16* wp = (bf16*)(ws + XPAD_BYTES);               // 1,179,648 B
  float* alpha = (float*)(ws + XPAD_BYTES + WPK_BYTES);  // 1,024 B

  pack_w_kernel<<<C_, 256, 0, stream>>>(w1, w2, wp, alpha);
  pack_x_kernel<<<B_ * HP, 256, 0, stream>>>(input, xp);  // covers halo; no memset
  gemm_kernel<<<M_TOT / 128 * (C_ / 128), 256, 0, stream>>>(xp, wp, alpha, out);
}

// Round 3
// 251.600 us; speedup vs baseline: 1.4795x; 1.1587x over previous
//
#include <hip/hip_runtime.h>
#include <hip/hip_bf16.h>

// Problem constants
#define B_    32
#define C_    256     // Cin == Cout
#define H_    56
#define W_    56
#define HP    58      // padded H
#define WPAD  58      // padded W
#define HW    3136    // H_*W_
#define CHW   802816  // C_*H_*W_
#define M_TOT 100352  // B_*H_*W_

typedef char charx16 __attribute__((ext_vector_type(16)));
typedef int  intx4   __attribute__((ext_vector_type(4)));

#define XPAD_BYTES (B_ * HP * WPAD * C_)        // 27,557,888 (i8)
#define WPK_BYTES  (C_ * 9 * C_)                // 589,824 (i8)

// ---------------------------------------------------------------------------
// Pack weights: wq[co][s][ci] i8 = sign(w1)+sign(w2) in {-2..2} (= 2*w_ter),
// alphah[co] = 0.5 * (mean|w1| + mean|w2|)  -> out = i32acc * alphah.
// ---------------------------------------------------------------------------
__global__ __launch_bounds__(256) void pack_w_kernel(const float* __restrict__ w1,
                                                     const float* __restrict__ w2,
                                                     char* __restrict__ wq,
                                                     float* __restrict__ alphah) {
  const int co = blockIdx.x;
  const int ci = threadIdx.x;
  const int base = (co * C_ + ci) * 9;
  float sabs = 0.f;
#pragma unroll
  for (int s = 0; s < 9; ++s) {
    const float a = w1[base + s];
    const float b = w2[base + s];
    const int sa = (a > 0.f) - (a < 0.f);
    const int sb = (b > 0.f) - (b < 0.f);
    wq[(co * 9 + s) * C_ + ci] = (char)(sa + sb);
    sabs += fabsf(a) + fabsf(b);
  }
#pragma unroll
  for (int off = 32; off > 0; off >>= 1) sabs += __shfl_down(sabs, off, 64);
  __shared__ float red[4];
  if ((threadIdx.x & 63) == 0) red[threadIdx.x >> 6] = sabs;
  __syncthreads();
  if (threadIdx.x == 0)
    alphah[co] = (red[0] + red[1] + red[2] + red[3]) * (0.5f / 2304.0f);
}

// ---------------------------------------------------------------------------
// Pack input: sign(x) NCHW fp32 -> padded NHWC i8 [B][58][58][C].
// One block per (b, padded-y). LDS tile [x_pad][ci], row stride 272 B
// (17 granules, odd -> bank spread without explicit swizzle). b128 LDS
// writes (16 ci / thread / iter) and b128 global stores. Halo zero-filled.
// ---------------------------------------------------------------------------
#define ROWPC 272
__global__ __launch_bounds__(256) void pack_x_kernel(const float* __restrict__ in,
                                                     char* __restrict__ xp) {
  __shared__ char row[58 * ROWPC];  // 15,776 B
  const int yp = blockIdx.x % HP;
  const int b  = blockIdx.x / HP;
  const int tid = threadIdx.x;

  // zero-fill tile (covers halo + invalid-y rows)
  float4* rz = (float4*)row;
  const float4 z4 = make_float4(0.f, 0.f, 0.f, 0.f);
#pragma unroll
  for (int i = 0; i < 4; ++i) {
    const int idx = i * 256 + tid;
    if (idx < (58 * ROWPC) / 16) rz[idx] = z4;
  }
  __syncthreads();

  const int y = yp - 1;
  const int x = tid & 63;     // lane-per-x: coalesced fp32 reads
  const int cig = tid >> 6;   // 0..3
  if (y >= 0 && y < H_ && x < W_) {
    const float* src = in + ((size_t)(b * C_) * H_ + y) * W_ + x;
#pragma unroll
    for (int it = 0; it < 4; ++it) {
      const int ci0 = it * 64 + cig * 16;
      charx16 v;
#pragma unroll
      for (int j = 0; j < 16; ++j) {
        const float f = src[(size_t)(ci0 + j) * HW];
        v[j] = (char)((f > 0.f) - (f < 0.f));
      }
      *(charx16*)&row[(x + 1) * ROWPC + ci0] = v;  // 16B LDS write
    }
  }
  __syncthreads();

  // write padded row: 58 x-slots x 256 B, b128 stores
  const int cc = tid & 15;   // 16 chunks = full 256 B ci-row
  const int xo = tid >> 4;   // 16 x per iter
  char* dst = xp + (size_t)(b * HP + yp) * WPAD * C_;
#pragma unroll
  for (int it = 0; it < 4; ++it) {
    const int xs = it * 16 + xo;
    if (xs < WPAD)
      *(float4*)(dst + xs * C_ + cc * 16) = *(const float4*)&row[xs * ROWPC + cc * 16];
  }
}

// ---------------------------------------------------------------------------
// Implicit-GEMM conv, int8: C[co][m] = sum_{s,ci} Wq[co][s][ci]*Xq[m(+s)][ci]
// Tile 128(co) x 128(m), BK=128, 4 waves of 64x64, mfma_i32_16x16x64_i8.
// LDS 16B-chunk XOR swizzle (chunk ^= row&7) -> 2-way (free) b128 reads.
// 18 steps (9 shifts x 2 ci-halves) = half the barriers of the bf16 version.
// ---------------------------------------------------------------------------
__global__ __launch_bounds__(256, 3) void gemm_kernel(const char* __restrict__ xp,
                                                      const char* __restrict__ wq,
                                                      const float* __restrict__ alphah,
                                                      float* __restrict__ out) {
  __shared__ char sA[128 * 128];  // weight tile [co 128][k 128B]
  __shared__ char sB[128 * 128];  // input tile  [m 128][k 128B]
  const int tid = threadIdx.x;

  // XCD-paired decode: blocks id, id+8 are the two co-halves of one m-tile.
  const int id = blockIdx.x;
  const int xcd = id & 7;
  const int l = id >> 3;
  const int co0 = (l & 1) * 128;
  const int m0 = ((l >> 1) * 8 + xcd) * 128;

  const int srow = tid >> 3;                 // staging row 0..31 (+32*i)
  const int scol = (tid & 7) ^ (srow & 7);   // XOR-swizzled source chunk

  const char* wsrc[4];
  const char* xsrc[4];
#pragma unroll
  for (int i = 0; i < 4; ++i) {
    const int m = m0 + srow + 32 * i;
    const int b = m / HW;
    const int rem = m - b * HW;
    const int y = rem / W_;
    const int x = rem - y * W_;
    xsrc[i] = xp + ((b * HP + y) * WPAD + x) * C_ + scol * 16;
    wsrc[i] = wq + (co0 + srow + 32 * i) * 9 * C_ + scol * 16;
  }

  intx4 acc[4][4] = {};

  const int lane = tid & 63;
  const int wave = tid >> 6;
  const int wm = wave >> 1;   // co 64-half
  const int wn = wave & 1;    // m 64-half
  const int lrow = lane & 15;
  const int quad = lane >> 4;
  const int swk = lrow & 7;
  const int abase = (wm * 64 + lrow) * 128;
  const int bbase = (wn * 64 + lrow) * 128;

  for (int s = 0; s < 9; ++s) {
    const int woff = s * C_;
    const int shoff = ((s / 3) * WPAD + (s % 3)) * C_;
#pragma unroll
    for (int h = 0; h < 2; ++h) {
      const int hh = h * 128;
      __syncthreads();  // previous tile's MFMA reads done
#pragma unroll
      for (int i = 0; i < 4; ++i) {
        __builtin_amdgcn_global_load_lds(
            (const __attribute__((address_space(1))) void*)(wsrc[i] + woff + hh),
            (__attribute__((address_space(3))) void*)(sA + i * 4096 + tid * 16),
            16, 0, 0);
      }
#pragma unroll
      for (int i = 0; i < 4; ++i) {
        __builtin_amdgcn_global_load_lds(
            (const __attribute__((address_space(1))) void*)(xsrc[i] + shoff + hh),
            (__attribute__((address_space(3))) void*)(sB + i * 4096 + tid * 16),
            16, 0, 0);
      }
      __syncthreads();  // vmcnt(0) drained before barrier -> data ready
#pragma unroll
      for (int kf = 0; kf < 2; ++kf) {
        const int coff = (((kf << 2) + quad) ^ swk) << 4;  // swizzled chunk
        intx4 af[4], bfv[4];
#pragma unroll
        for (int i = 0; i < 4; ++i)
          af[i] = *(const intx4*)(sA + abase + i * 2048 + coff);
#pragma unroll
        for (int j = 0; j < 4; ++j)
          bfv[j] = *(const intx4*)(sB + bbase + j * 2048 + coff);
#pragma unroll
        for (int i = 0; i < 4; ++i)
#pragma unroll
          for (int j = 0; j < 4; ++j)
            acc[i][j] = __builtin_amdgcn_mfma_i32_16x16x64_i8(af[i], bfv[j],
                                                              acc[i][j], 0, 0, 0);
      }
    }
  }

  // Epilogue: D row (quad*4+r) = co dim, D col (lane&15) = spatial m dim.
  int ob[4];
#pragma unroll
  for (int j = 0; j < 4; ++j) {
    const int m = m0 + wn * 64 + j * 16 + lrow;
    const int b = m / HW;
    const int rem = m - b * HW;
    const int y = rem / W_;
    const int x = rem - y * W_;
    ob[j] = b * CHW + y * W_ + x;
  }
#pragma unroll
  for (int i = 0; i < 4; ++i) {
#pragma unroll
    for (int r = 0; r < 4; ++r) {
      const int co = co0 + wm * 64 + i * 16 + quad * 4 + r;
      const float sc = alphah[co];
#pragma unroll
      for (int j = 0; j < 4; ++j)
        out[ob[j] + co * HW] = (float)acc[i][j][r] * sc;
    }
  }
}

// ---------------------------------------------------------------------------
extern "C" void kernel_launch(void* const* d_in, const int* in_sizes, int n_in,
                              void* d_out, int out_size, void* d_ws, size_t ws_size,
                              hipStream_t stream) {
  const float* input = (const float*)d_in[0];
  const float* w1 = (const float*)d_in[1];
  const float* w2 = (const float*)d_in[2];
  float* out = (float*)d_out;

  char* ws = (char*)d_ws;
  char* xp = ws;                                    // 27,557,888 B
  char* wq = ws + XPAD_BYTES;                       // 589,824 B
  float* alphah = (float*)(ws + XPAD_BYTES + WPK_BYTES);  // 1,024 B

  pack_w_kernel<<<C_, 256, 0, stream>>>(w1, w2, wq, alphah);
  pack_x_kernel<<<B_ * HP, 256, 0, stream>>>(input, xp);
  gemm_kernel<<<M_TOT / 128 * (C_ / 128), 256, 0, stream>>>(xp, wq, alphah, out);
}

// Round 4
// 248.647 us; speedup vs baseline: 1.4971x; 1.0119x over previous
//
#include <hip/hip_runtime.h>
#include <hip/hip_bf16.h>

// Problem constants
#define B_    32
#define C_    256     // Cin == Cout
#define H_    56
#define W_    56
#define HP    58      // padded H
#define WPAD  58      // padded W
#define HW    3136    // H_*W_
#define CHW   802816  // C_*H_*W_
#define M_TOT 100352  // B_*H_*W_

typedef char  charx16 __attribute__((ext_vector_type(16)));
typedef int   intx4   __attribute__((ext_vector_type(4)));

#define XPAD_BYTES (B_ * HP * WPAD * C_)        // 27,557,888 (i8)
#define WPK_BYTES  (C_ * 9 * C_)                // 589,824 (i8)

__device__ __forceinline__ int sgn8(float f) {
  return ((f > 0.f) ? 1 : ((f < 0.f) ? -1 : 0)) & 0xff;
}

// ---------------------------------------------------------------------------
// Pack weights: wq[co][s][ci] i8 = sign(w1)+sign(w2) in {-2..2} (= 2*w_ter),
// alphah[co] = 0.5*(mean|w1|+mean|w2|). Coalesced loads via LDS stage.
// ---------------------------------------------------------------------------
__global__ __launch_bounds__(256) void pack_w_kernel(const float* __restrict__ w1,
                                                     const float* __restrict__ w2,
                                                     char* __restrict__ wq,
                                                     float* __restrict__ alphah) {
  __shared__ float l1[2304], l2[2304];
  const int co = blockIdx.x;
  const int tid = threadIdx.x;
  const float* s1 = w1 + co * 2304;
  const float* s2 = w2 + co * 2304;
#pragma unroll
  for (int i = 0; i < 9; ++i) {       // stride-1 across lanes: coalesced
    l1[i * 256 + tid] = s1[i * 256 + tid];
    l2[i * 256 + tid] = s2[i * 256 + tid];
  }
  __syncthreads();
  const int ci = tid;
  float sabs = 0.f;
#pragma unroll
  for (int s = 0; s < 9; ++s) {       // LDS stride 9 (odd) -> bank-spread
    const float a = l1[ci * 9 + s];
    const float b = l2[ci * 9 + s];
    const int sa = (a > 0.f) - (a < 0.f);
    const int sb = (b > 0.f) - (b < 0.f);
    wq[(co * 9 + s) * C_ + ci] = (char)(sa + sb);   // coalesced byte store
    sabs += fabsf(a) + fabsf(b);
  }
#pragma unroll
  for (int off = 32; off > 0; off >>= 1) sabs += __shfl_down(sabs, off, 64);
  __shared__ float red[4];
  if ((tid & 63) == 0) red[tid >> 6] = sabs;
  __syncthreads();
  if (tid == 0)
    alphah[co] = (red[0] + red[1] + red[2] + red[3]) * (0.5f / 2304.0f);
}

// ---------------------------------------------------------------------------
// Pack input: sign(x) NCHW fp32 -> padded NHWC i8 [B][58][58][C].
// One block per (b, padded-y). float4 global reads (16B/lane, coalesced
// 224B segments), pack 4-ci bytes -> b32 LDS writes into [x_pad][ci] tile,
// b128 global stores. Halo zero-filled here (no memset needed).
// ---------------------------------------------------------------------------
#define ROWPC 272
__global__ __launch_bounds__(256) void pack_x_kernel(const float* __restrict__ in,
                                                     char* __restrict__ xp) {
  __shared__ char row[58 * ROWPC];  // 15,776 B
  const int yp = blockIdx.x % HP;
  const int b  = blockIdx.x / HP;
  const int tid = threadIdx.x;

  // zero-fill tile (covers halo + invalid-y rows)
  float4* rz = (float4*)row;
  const float4 z4 = make_float4(0.f, 0.f, 0.f, 0.f);
#pragma unroll
  for (int i = 0; i < 4; ++i) {
    const int idx = i * 256 + tid;
    if (idx < (58 * ROWPC) / 16) rz[idx] = z4;
  }
  __syncthreads();

  const int y = yp - 1;
  const int xq = tid % 14;   // x quad: x = xq*4 .. xq*4+3
  const int cs = tid / 14;   // ci-quad slot 0..18 (252..255 idle)
  if (y >= 0 && y < H_ && cs < 18) {
    const float* base = in + ((size_t)b * C_ * H_ + (size_t)y) * W_ + xq * 4;
#pragma unroll
    for (int k = 0; k < 4; ++k) {
      const int cq = cs + 18 * k;          // ci quad index 0..63
      if (cq < 64) {
        float4 f[4];
#pragma unroll
        for (int j = 0; j < 4; ++j)
          f[j] = *(const float4*)(base + (size_t)(cq * 4 + j) * (H_ * W_));
#pragma unroll
        for (int d = 0; d < 4; ++d) {
          const float v0 = (d == 0) ? f[0].x : (d == 1) ? f[0].y : (d == 2) ? f[0].z : f[0].w;
          const float v1 = (d == 0) ? f[1].x : (d == 1) ? f[1].y : (d == 2) ? f[1].z : f[1].w;
          const float v2 = (d == 0) ? f[2].x : (d == 1) ? f[2].y : (d == 2) ? f[2].z : f[2].w;
          const float v3 = (d == 0) ? f[3].x : (d == 1) ? f[3].y : (d == 2) ? f[3].z : f[3].w;
          const unsigned int pk = (unsigned)sgn8(v0) | ((unsigned)sgn8(v1) << 8) |
                                  ((unsigned)sgn8(v2) << 16) | ((unsigned)sgn8(v3) << 24);
          *(unsigned int*)&row[(xq * 4 + d + 1) * ROWPC + cq * 4] = pk;
        }
      }
    }
  }
  __syncthreads();

  // write padded row: 58 x-slots x 256 B, b128 stores
  const int cc = tid & 15;   // 16 chunks = full 256 B ci-row
  const int xo = tid >> 4;   // 16 x per iter
  char* dst = xp + (size_t)(b * HP + yp) * WPAD * C_;
#pragma unroll
  for (int it = 0; it < 4; ++it) {
    const int xs = it * 16 + xo;
    if (xs < WPAD)
      *(float4*)(dst + xs * C_ + cc * 16) = *(const float4*)&row[xs * ROWPC + cc * 16];
  }
}

// ---------------------------------------------------------------------------
// Implicit-GEMM conv, int8, DOUBLE-BUFFERED: one barrier per K-step; loads
// for step t+1 issue before compute(t), so the forced vmcnt(0)-at-barrier
// drain lands after a full compute phase. 18 steps (9 shifts x 2 ci-halves).
// Tile 128(co) x 128(m), 4 waves of 64x64, mfma_i32_16x16x64_i8.
// LDS 16B-chunk XOR swizzle -> conflict-free b128 reads. XCD-paired decode.
// ---------------------------------------------------------------------------
__global__ __launch_bounds__(256, 2) void gemm_kernel(const char* __restrict__ xp,
                                                      const char* __restrict__ wq,
                                                      const float* __restrict__ alphah,
                                                      float* __restrict__ out) {
  __shared__ char sA[2 * 128 * 128];  // weight tiles [buf][co 128][k 128B]
  __shared__ char sB[2 * 128 * 128];  // input tiles  [buf][m 128][k 128B]
  const int tid = threadIdx.x;

  // XCD-paired decode: blocks id, id+8 are the two co-halves of one m-tile.
  const int id = blockIdx.x;
  const int xcd = id & 7;
  const int l = id >> 3;
  const int co0 = (l & 1) * 128;
  const int m0 = ((l >> 1) * 8 + xcd) * 128;

  const int srow = tid >> 3;                 // staging row 0..31 (+32*i)
  const int scol = (tid & 7) ^ (srow & 7);   // XOR-swizzled source chunk

  const char* wsrc[4];
  const char* xsrc[4];
#pragma unroll
  for (int i = 0; i < 4; ++i) {
    const int m = m0 + srow + 32 * i;
    const int b = m / HW;
    const int rem = m - b * HW;
    const int y = rem / W_;
    const int x = rem - y * W_;
    xsrc[i] = xp + ((b * HP + y) * WPAD + x) * C_ + scol * 16;
    wsrc[i] = wq + (co0 + srow + 32 * i) * 9 * C_ + scol * 16;
  }

  intx4 acc[4][4] = {};

  const int lane = tid & 63;
  const int wave = tid >> 6;
  const int wm = wave >> 1;   // co 64-half
  const int wn = wave & 1;    // m 64-half
  const int lrow = lane & 15;
  const int quad = lane >> 4;
  const int swk = lrow & 7;
  const int abase = (wm * 64 + lrow) * 128;
  const int bbase = (wn * 64 + lrow) * 128;

  // stage tile t (s = t>>1, h = t&1) into buffer (t&1)
  auto stage = [&](int t) {
    const int s = t >> 1;
    const int hh = (t & 1) * 128;
    const int woff = s * C_ + hh;
    const int shoff = ((s / 3) * WPAD + (s % 3)) * C_ + hh;
    char* dA = sA + (t & 1) * 16384 + tid * 16;
    char* dB = sB + (t & 1) * 16384 + tid * 16;
#pragma unroll
    for (int i = 0; i < 4; ++i)
      __builtin_amdgcn_global_load_lds(
          (const __attribute__((address_space(1))) void*)(wsrc[i] + woff),
          (__attribute__((address_space(3))) void*)(dA + i * 4096), 16, 0, 0);
#pragma unroll
    for (int i = 0; i < 4; ++i)
      __builtin_amdgcn_global_load_lds(
          (const __attribute__((address_space(1))) void*)(xsrc[i] + shoff),
          (__attribute__((address_space(3))) void*)(dB + i * 4096), 16, 0, 0);
  };

  stage(0);
  for (int t = 0; t < 18; ++t) {
    __syncthreads();            // vmcnt(0)+lgkmcnt drain: buf[t&1] ready,
                                // buf[(t+1)&1] reads (step t-1) complete
    if (t < 17) stage(t + 1);   // in flight during compute(t)
    const char* bA = sA + (t & 1) * 16384;
    const char* bB = sB + (t & 1) * 16384;
#pragma unroll
    for (int kf = 0; kf < 2; ++kf) {
      const int coff = (((kf << 2) + quad) ^ swk) << 4;  // swizzled chunk
      intx4 af[4], bfv[4];
#pragma unroll
      for (int i = 0; i < 4; ++i)
        af[i] = *(const intx4*)(bA + abase + i * 2048 + coff);
#pragma unroll
      for (int j = 0; j < 4; ++j)
        bfv[j] = *(const intx4*)(bB + bbase + j * 2048 + coff);
#pragma unroll
      for (int i = 0; i < 4; ++i)
#pragma unroll
        for (int j = 0; j < 4; ++j)
          acc[i][j] = __builtin_amdgcn_mfma_i32_16x16x64_i8(af[i], bfv[j],
                                                            acc[i][j], 0, 0, 0);
    }
  }

  // Epilogue: D row (quad*4+r) = co dim, D col (lane&15) = spatial m dim.
  int ob[4];
#pragma unroll
  for (int j = 0; j < 4; ++j) {
    const int m = m0 + wn * 64 + j * 16 + lrow;
    const int b = m / HW;
    const int rem = m - b * HW;
    const int y = rem / W_;
    const int x = rem - y * W_;
    ob[j] = b * CHW + y * W_ + x;
  }
#pragma unroll
  for (int i = 0; i < 4; ++i) {
#pragma unroll
    for (int r = 0; r < 4; ++r) {
      const int co = co0 + wm * 64 + i * 16 + quad * 4 + r;
      const float sc = alphah[co];
#pragma unroll
      for (int j = 0; j < 4; ++j)
        out[ob[j] + co * HW] = (float)acc[i][j][r] * sc;
    }
  }
}

// ---------------------------------------------------------------------------
extern "C" void kernel_launch(void* const* d_in, const int* in_sizes, int n_in,
                              void* d_out, int out_size, void* d_ws, size_t ws_size,
                              hipStream_t stream) {
  const float* input = (const float*)d_in[0];
  const float* w1 = (const float*)d_in[1];
  const float* w2 = (const float*)d_in[2];
  float* out = (float*)d_out;

  char* ws = (char*)d_ws;
  char* xp = ws;                                    // 27,557,888 B
  char* wq = ws + XPAD_BYTES;                       // 589,824 B
  float* alphah = (float*)(ws + XPAD_BYTES + WPK_BYTES);  // 1,024 B

  pack_w_kernel<<<C_, 256, 0, stream>>>(w1, w2, wq, alphah);
  pack_x_kernel<<<B_ * HP, 256, 0, stream>>>(input, xp);
  gemm_kernel<<<M_TOT / 128 * (C_ / 128), 256, 0, stream>>>(xp, wq, alphah, out);
}